// Round 5
// baseline (357.962 us; speedup 1.0000x reference)
//
#include <hip/hip_runtime.h>

// CrossJointAttention fused kernel for MI355X (gfx950) -- Round 7.
// B=16384, N=12 joints, D=128, H=4, hd=32. fp32 in/out, bf16 MFMA internally.
//
// R7 vs R6 post-mortem: register prefetch of x is unwinnable (3 attempts,
// VGPR pinned at 84, prefetch always spilled to scratch: R6 still +90MB
// writes / +150MB reads). Decisive fact: per-round time ~24-28us was
// INVARIANT from R2..R6 while the entire phase-1 input path changed ->
// the cost lives in phase 2's serial LDS chains + barriers.
//  - Phase 2 rewritten: SWAPPED QK MFMA(kb,qa) puts scores for query n=lm
//    lane-local across keys m=lq*4+r. Softmax fully in registers:
//    row-sum = 3 adds + 2 shfl_xor (was 4); 1/l lane-local (rls deleted);
//    P^T fragment for PV assembled by 2 bf16-packs + 4 __shfl gathers
//    (P LDS array deleted; no lgkm round-trips; 4 heads fully independent
//    ILP, no serialization through a shared P buffer).
//  - prep_x dropped (cost ~30us at bench level for a measured -4.5us gain);
//    phase 1 back to R2-proven fp32 x loads + pack (84 VGPR, no spill).
//  - Deferred output stores dropped (live-across-barrier state ~0; suspected
//    spill contributor at the 84-reg budget). Stores posted in phase 3.
//  - Kept: persistent grid 768 + grid-stride, one-time prologue, vT zero-pad
//    (guards 0*garbage=NaN in PV), VPAD=20 conflict-free vT.
// Numerics bit-compatible: same RNE bf16, same MFMA fragment layouts; only
// the f32 summation order of the softmax denominator changes (tree shape).

typedef unsigned short u16;
typedef short bf16x8 __attribute__((ext_vector_type(8)));   // 8 bf16 = 4 VGPRs
typedef short bf16x4 __attribute__((ext_vector_type(4)));   // 4 bf16 = 2 VGPRs
typedef float f32x4 __attribute__((ext_vector_type(4)));
typedef unsigned int u32x4 __attribute__((ext_vector_type(4)));

#define MFMA(a, b, c) __builtin_amdgcn_mfma_f32_16x16x32_bf16((a), (b), (c), 0, 0, 0)

#define BPW   4            // batches per group
#define ROWS  (BPW * 12)   // 48 joint-rows per group
#define XPAD  136          // row stride (bf16) for q/k/ctx: 272B, 16B-aligned
#define VPAD  20           // vT row stride: 40B -> bank coeff 10 (odd*2), 8B-aligned
#define NGRP  4096         // total batch-groups (16384 / BPW)
#define GRID  768          // 3 WG/CU x 256 CU -- exact residency fill

struct SMem {
    u16   qs[ROWS * XPAD];       // q rows [48][128]; ctx overlays per-head
    u16   ks[ROWS * XPAD];       // k rows
    u16   vT[BPW * 128 * VPAD];  // per batch [feat][joint pad 20]; cols 12..19 zeroed once
    float bias_s[16 * 16];       // adj*scale*log2e; -1e30 for m>=12; 0 for n>=12
    float bvec[4 * 128];         // bq | bk | bv | bo
};                               // 49,664 B -> 3 WG/CU (limit 54,613)

__device__ __forceinline__ u16 f2b(float f) {   // fp32 -> bf16 RNE
    unsigned u = __builtin_bit_cast(unsigned, f);
    return (u16)((u + 0x7fffu + ((u >> 16) & 1u)) >> 16);
}

__device__ __forceinline__ void st4(u16* p, float a, float b, float c, float d) {
    ushort4 v; v.x = f2b(a); v.y = f2b(b); v.z = f2b(c); v.w = f2b(d);
    *(ushort4*)p = v;   // ds_write_b64
}

__device__ __forceinline__ bf16x8 pack8(float4 a, float4 b) {
    bf16x8 r;
    r[0] = (short)f2b(a.x); r[1] = (short)f2b(a.y);
    r[2] = (short)f2b(a.z); r[3] = (short)f2b(a.w);
    r[4] = (short)f2b(b.x); r[5] = (short)f2b(b.y);
    r[6] = (short)f2b(b.z); r[7] = (short)f2b(b.w);
    return r;
}

__global__ void prep_w(const float* __restrict__ Wq, const float* __restrict__ Wk,
                       const float* __restrict__ Wv, const float* __restrict__ Wo,
                       u16* __restrict__ wbf) {
    int i = blockIdx.x * 256 + threadIdx.x;     // 0..16383
    wbf[i]         = f2b(Wq[i]);
    wbf[16384 + i] = f2b(Wk[i]);
    wbf[32768 + i] = f2b(Wv[i]);
    wbf[49152 + i] = f2b(Wo[i]);
}

__global__ __launch_bounds__(256, 3) void cja_main(
    const float* __restrict__ x, const float* __restrict__ vis,
    const float* __restrict__ bq, const float* __restrict__ bk,
    const float* __restrict__ bv, const float* __restrict__ bo,
    const float* __restrict__ bias_scale, const float* __restrict__ adj,
    const u16* __restrict__ wbf, float* __restrict__ out)
{
    extern __shared__ char smraw[];
    SMem& sm = *(SMem*)smraw;

    const int tid  = threadIdx.x;
    const int wave = tid >> 6;
    const int lane = tid & 63;
    const int lq   = lane >> 4;      // quadrant 0..3
    const int lm   = lane & 15;      // 0..15

    // ---------------- One-time prologue -------------------------------------
    for (int i = tid; i < BPW * 128; i += 256) {          // zero vT cols 12..19
        unsigned* d = (unsigned*)(sm.vT + i * VPAD + 12); // byte 40i+24: 8B-aligned
        d[0] = 0u; d[1] = 0u; d[2] = 0u; d[3] = 0u;       // scatter never touches these
    }
    const float L2E = 1.4426950408889634f;
    {
        float scale = bias_scale[0] * L2E;
        int n = tid >> 4, m = tid & 15;
        float bval;
        if (m >= 12)     bval = -1e30f;                   // key-pad mask (exp2 -> 0)
        else if (n < 12) bval = adj[n * 12 + m] * scale;
        else             bval = 0.0f;                     // row pad: keep finite
        sm.bias_s[tid] = bval;
        if (tid < 128) {
            sm.bvec[tid]       = bq[tid];
            sm.bvec[128 + tid] = bk[tid];
            sm.bvec[256 + tid] = bv[tid];
            sm.bvec[384 + tid] = bo[tid];
        }
    }
    __syncthreads();

    // ---- round-invariant phase-2/3 addressing ------------------------------
    const int bl  = wave;
    const int nql = (lm < 12) ? lm : 11;                  // clamp: no OOB reads
    const u16* qrowp = sm.qs + (bl * 12 + nql) * XPAD;
    const u16* krowp = sm.ks + (bl * 12 + nql) * XPAD;
    const u16* vTb = sm.vT + bl * (128 * VPAD);
    const int mrow0 = wave * 32 + lm;                     // weight row (feature)
    const int mrow1 = mrow0 + 16;
    // swapped-QK score layout: lane holds scores for query n=lm, keys m=lq*4+r
    float biasv[4];
    #pragma unroll
    for (int rr = 0; rr < 4; rr++) biasv[rr] = sm.bias_s[lm * 16 + lq * 4 + rr];
    // P^T gather sources: pb word j <- word (j&1) of lane (2*lq + (j>>1))*16+lm
    const int s0 = ((lq << 1) << 4) + lm;
    const int s1 = s0 + 16;
    const float vc = (lq < 3) ? 10.0f * L2E : 0.0f;       // vis coeff (0 for pad keys)

    #pragma unroll 1
    for (int grp = blockIdx.x; grp < NGRP; grp += GRID) {
        const int  b0      = grp * BPW;
        const bool hasNext = (grp + GRID) < NGRP;

        // visibility for this wave's batch: one aligned float4 (keys lq*4..+3)
        const float* vp = vis + (size_t)(b0 + bl) * 12 + (lq < 3 ? lq * 4 : 0);
        float4 vv = *(const float4*)vp;                   // issued early, used in P2

        // ---------------- Phase 1: fused Q/K/V GEMMs (x fp32 + pack) --------
        {
            const u16* Wq_b = wbf;
            const u16* Wk_b = wbf + 16384;
            const u16* Wv_b = wbf + 32768;
            const float* xw = x + (size_t)b0 * 1536;      // 12*128 per batch
            f32x4 accq[2][3], acck[2][3], accv[3][2];
            #pragma unroll
            for (int i = 0; i < 2; i++)
                #pragma unroll
                for (int j = 0; j < 3; j++) { accq[i][j] = (f32x4){0,0,0,0}; acck[i][j] = (f32x4){0,0,0,0}; }
            #pragma unroll
            for (int i = 0; i < 3; i++)
                #pragma unroll
                for (int j = 0; j < 2; j++) accv[i][j] = (f32x4){0,0,0,0};
            #pragma unroll
            for (int ks2 = 0; ks2 < 4; ks2++) {
                const int koff = ks2 * 32 + lq * 8;
                bf16x8 xt[3];
                #pragma unroll
                for (int nt = 0; nt < 3; nt++) {
                    const float* xp = xw + (nt * 16 + lm) * 128 + koff;
                    float4 u0 = *(const float4*)xp;
                    float4 u1 = *(const float4*)(xp + 4);
                    xt[nt] = pack8(u0, u1);
                }
                bf16x8 wq0 = *(const bf16x8*)(Wq_b + mrow0 * 128 + koff);
                bf16x8 wq1 = *(const bf16x8*)(Wq_b + mrow1 * 128 + koff);
                bf16x8 wk0 = *(const bf16x8*)(Wk_b + mrow0 * 128 + koff);
                bf16x8 wk1 = *(const bf16x8*)(Wk_b + mrow1 * 128 + koff);
                bf16x8 wv0 = *(const bf16x8*)(Wv_b + mrow0 * 128 + koff);
                bf16x8 wv1 = *(const bf16x8*)(Wv_b + mrow1 * 128 + koff);
                #pragma unroll
                for (int nt = 0; nt < 3; nt++) {
                    accq[0][nt] = MFMA(wq0, xt[nt], accq[0][nt]);   // C[e,n] = Wq . x^T
                    accq[1][nt] = MFMA(wq1, xt[nt], accq[1][nt]);
                    acck[0][nt] = MFMA(wk0, xt[nt], acck[0][nt]);
                    acck[1][nt] = MFMA(wk1, xt[nt], acck[1][nt]);
                    accv[nt][0] = MFMA(xt[nt], wv0, accv[nt][0]);   // C[n,e] = x . Wv^T
                    accv[nt][1] = MFMA(xt[nt], wv1, accv[nt][1]);
                }
            }
            // epilogue Q/K: transposed store -> q,k row-major [joint-row][feat]
            #pragma unroll
            for (int mi = 0; mi < 2; mi++) {
                const int e0 = (wave * 2 + mi) * 16 + lq * 4;
                float bq0 = sm.bvec[e0], bq1 = sm.bvec[e0+1], bq2 = sm.bvec[e0+2], bq3 = sm.bvec[e0+3];
                float bk0 = sm.bvec[128+e0], bk1 = sm.bvec[128+e0+1], bk2 = sm.bvec[128+e0+2], bk3 = sm.bvec[128+e0+3];
                #pragma unroll
                for (int nt = 0; nt < 3; nt++) {
                    const int n = nt * 16 + lm;                   // joint-row 0..47
                    st4(sm.qs + n * XPAD + e0, accq[mi][nt][0]+bq0, accq[mi][nt][1]+bq1,
                                               accq[mi][nt][2]+bq2, accq[mi][nt][3]+bq3);
                    st4(sm.ks + n * XPAD + e0, acck[mi][nt][0]+bk0, acck[mi][nt][1]+bk1,
                                               acck[mi][nt][2]+bk2, acck[mi][nt][3]+bk3);
                }
            }
            // epilogue V: scatter -> vT[batch][feat][joint], stride 20 (conflict-free)
            #pragma unroll
            for (int nt2 = 0; nt2 < 2; nt2++) {
                const int e = (wave * 2 + nt2) * 16 + lm;         // feature column
                const float bvv = sm.bvec[256 + e];
                #pragma unroll
                for (int mt = 0; mt < 3; mt++) {
                    #pragma unroll
                    for (int r = 0; r < 4; r++) {
                        int n = mt * 16 + lq * 4 + r;             // joint-row 0..47
                        int bb = n / 12, j = n - bb * 12;
                        sm.vT[bb * (128 * VPAD) + e * VPAD + j] = f2b(accv[mt][nt2][r] + bvv);
                    }
                }
            }
        }
        __syncthreads();   // B1

        // ---------------- Phase 2: attention, softmax fully in registers ----
        {
            const float SC2 = 0.2550348606381560f;        // (1/sqrt(32))*log2(e)
            const bf16x8 z8 = {0,0,0,0,0,0,0,0};
            float visr[4];
            visr[0] = vc * (1.0f - vv.x); visr[1] = vc * (1.0f - vv.y);
            visr[2] = vc * (1.0f - vv.z); visr[3] = vc * (1.0f - vv.w);
            #pragma unroll
            for (int h = 0; h < 4; h++) {
                bf16x8 qa = *(const bf16x8*)(qrowp + h * 32 + lq * 8);
                bf16x8 kb = *(const bf16x8*)(krowp + h * 32 + lq * 8);
                // swapped operands: D[row=m=lq*4+r, col=n=lm] = K[m].Q[n]
                f32x4 sc = MFMA(kb, qa, ((f32x4){0,0,0,0}));
                float e0 = __builtin_amdgcn_exp2f(sc[0] * SC2 + biasv[0] - visr[0]);
                float e1 = __builtin_amdgcn_exp2f(sc[1] * SC2 + biasv[1] - visr[1]);
                float e2 = __builtin_amdgcn_exp2f(sc[2] * SC2 + biasv[2] - visr[2]);
                float e3 = __builtin_amdgcn_exp2f(sc[3] * SC2 + biasv[3] - visr[3]);
                float l = (e0 + e1) + (e2 + e3);          // partial sum over own 4 keys
                l += __shfl_xor(l, 16);                   // + lq^1 group
                l += __shfl_xor(l, 32);                   // + lq^2 groups -> full sum
                float rln = __builtin_amdgcn_rcpf(l);     // 1/l for query n=lm, lane-local
                // pack P (bf16 RNE, identical to old LDS path) and gather P^T frag
                unsigned w0 = (unsigned)f2b(e0) | ((unsigned)f2b(e1) << 16);
                unsigned w1 = (unsigned)f2b(e2) | ((unsigned)f2b(e3) << 16);
                unsigned p0 = (unsigned)__shfl((int)w0, s0);
                unsigned p1 = (unsigned)__shfl((int)w1, s0);
                unsigned p2 = (unsigned)__shfl((int)w0, s1);
                unsigned p3 = (unsigned)__shfl((int)w1, s1);
                u32x4 pw;
                pw[0] = (lq < 2) ? p0 : 0u;  pw[1] = (lq < 2) ? p1 : 0u;
                pw[2] = (lq < 2) ? p2 : 0u;  pw[3] = (lq < 2) ? p3 : 0u;
                bf16x8 pb = __builtin_bit_cast(bf16x8, pw);   // B[k=m, col=n=lm]
                #pragma unroll
                for (int mt = 0; mt < 2; mt++) {
                    bf16x8 va = z8;
                    if (lq < 2) {                          // A[row=feat, k=m]; quads 2,3 zero
                        const bf16x4* vp2 = (const bf16x4*)(vTb + (h * 32 + mt * 16 + lm) * VPAD + lq * 8);
                        va = __builtin_shufflevector(vp2[0], vp2[1], 0, 1, 2, 3, 4, 5, 6, 7);
                    }
                    f32x4 c = MFMA(va, pb, ((f32x4){0,0,0,0}));   // C[e',n]
                    if (lm < 12) {                                 // ctx overlays qs
                        u16* d = sm.qs + (bl * 12 + lm) * XPAD + h * 32 + mt * 16 + lq * 4;
                        st4(d, c[0] * rln, c[1] * rln, c[2] * rln, c[3] * rln);
                    }
                }
            }
        }
        __syncthreads();   // B2

        // ---------------- Phase 3: output projection + store ----------------
        {
            const u16* Wo_b = wbf + 49152;
            f32x4 acc[2][3];
            #pragma unroll
            for (int i = 0; i < 2; i++)
                #pragma unroll
                for (int j = 0; j < 3; j++) acc[i][j] = (f32x4){0,0,0,0};
            #pragma unroll
            for (int ks2 = 0; ks2 < 4; ks2++) {
                const int koff = ks2 * 32 + lq * 8;
                bf16x8 a0 = *(const bf16x8*)(Wo_b + mrow0 * 128 + koff);
                bf16x8 a1 = *(const bf16x8*)(Wo_b + mrow1 * 128 + koff);
                #pragma unroll
                for (int nt = 0; nt < 3; nt++) {
                    bf16x8 bfr = *(const bf16x8*)(sm.qs + (nt * 16 + lm) * XPAD + koff);
                    acc[0][nt] = MFMA(a0, bfr, acc[0][nt]);
                    acc[1][nt] = MFMA(a1, bfr, acc[1][nt]);
                }
            }
            #pragma unroll
            for (int mi = 0; mi < 2; mi++) {
                const int e0 = (wave * 2 + mi) * 16 + lq * 4;
                float bo0 = sm.bvec[384+e0], bo1 = sm.bvec[384+e0+1],
                      bo2 = sm.bvec[384+e0+2], bo3 = sm.bvec[384+e0+3];
                #pragma unroll
                for (int nt = 0; nt < 3; nt++) {
                    const int n = nt * 16 + lm;                    // joint-row 0..47
                    float4 o;
                    o.x = acc[mi][nt][0] + bo0;
                    o.y = acc[mi][nt][1] + bo1;
                    o.z = acc[mi][nt][2] + bo2;
                    o.w = acc[mi][nt][3] + bo3;
                    *(float4*)(out + ((size_t)(b0 * 12 + n) << 7) + e0) = o;
                }
            }
        }
        if (hasNext) __syncthreads();   // B3: protect qs/ks/vT for next P1
    }
}

extern "C" void kernel_launch(void* const* d_in, const int* in_sizes, int n_in,
                              void* d_out, int out_size, void* d_ws, size_t ws_size,
                              hipStream_t stream) {
    const float* x   = (const float*)d_in[0];
    const float* vis = (const float*)d_in[1];
    const float* Wq  = (const float*)d_in[2];
    const float* bq  = (const float*)d_in[3];
    const float* Wk  = (const float*)d_in[4];
    const float* bk  = (const float*)d_in[5];
    const float* Wv  = (const float*)d_in[6];
    const float* bv  = (const float*)d_in[7];
    const float* Wo  = (const float*)d_in[8];
    const float* bo  = (const float*)d_in[9];
    const float* bs  = (const float*)d_in[10];
    const float* adj = (const float*)d_in[11];
    u16* wbf = (u16*)d_ws;   // 4 x 128x128 bf16 = 128KB

    prep_w<<<64, 256, 0, stream>>>(Wq, Wk, Wv, Wo, wbf);
    cja_main<<<GRID, 256, sizeof(SMem), stream>>>(
        x, vis, bq, bk, bv, bo, bs, adj, wbf, (float*)d_out);
}

// Round 6
// 316.475 us; speedup vs baseline: 1.1311x; 1.1311x over previous
//
#include <hip/hip_runtime.h>

// CrossJointAttention fused kernel for MI355X (gfx950) -- Round 8.
// B=16384, N=12 joints, D=128, H=4, hd=32. fp32 in/out, bf16 MFMA internally.
//
// R8 vs R7 post-mortem: in-register softmax regressed (serial shfl chain
// feeding PV); reverted to R2/R6's proven LDS-P phase 2. Root model from
// counters: per-round 24us at 22% issue-busy = per-wave serial global-load
// latency (84-VGPR allocator batches the 24 x-loads ~4x, each exposing
// 600-900cy) + full vmcnt drains at every barrier. Register prefetch of x
// is unwinnable (R4/R5/R6: always spilled). Fix: prefetch through LDS.
//  - x staged bf16 (prep_x) via global_load_lds (ZERO VGPRs) into an overlay
//    of the vT region: stage for round r+1 issues right after B2 (PV reads
//    done), drains at B3; P1 reads MFMA-ready frags via ds_read_b128
//    (~120cy, no pack VALU, no register batching).
//  - Raw s_barrier + lgkmcnt(0)-only at B1a/B1/B2 (no vmcnt drain); B3 is
//    the single full __syncthreads (drains stage + out stores).
//  - vT pad correctness under overlay: pads in the staged region get finite
//    bf16 x-garbage each round (multiplied by P=0 -> exact 0); pads beyond
//    the staged 13312B are zeroed once and never overwritten.
//  - No loop-carried register state (immediate stores) -> nothing to spill.
// Numerics identical to R2/R6 (same RNE bf16 via prep_x, same layouts).

typedef unsigned short u16;
typedef short bf16x8 __attribute__((ext_vector_type(8)));   // 8 bf16 = 4 VGPRs
typedef short bf16x4 __attribute__((ext_vector_type(4)));   // 4 bf16 = 2 VGPRs
typedef float f32x4 __attribute__((ext_vector_type(4)));

#define MFMA(a, b, c) __builtin_amdgcn_mfma_f32_16x16x32_bf16((a), (b), (c), 0, 0, 0)

#define BPW   4            // batches per group
#define ROWS  (BPW * 12)   // 48 joint-rows per group
#define XPAD  136          // row stride (bf16) for q/k/ctx/xs: 272B, 16B-aligned
#define VPAD  20           // vT row stride: 40B -> bank coeff 10 (odd*2), 8B-aligned
#define PPAD  20           // P row stride
#define NGRP  4096         // total batch-groups (16384 / BPW)
#define GRID  768          // 3 WG/CU x 256 CU -- exact residency fill
#define XS_BYTES (ROWS * XPAD * 2)       // 13056B staged x (bf16, padded rows)
#define XS_CHUNKS 13                      // ceil(13056 / 1024)

struct SMem {
    u16   qs[ROWS * XPAD];       // q rows [48][128]; ctx overlays per-head
    u16   ks[ROWS * XPAD];       // k rows
    u16   vT[BPW * 128 * VPAD];  // [batch][feat][joint p20]; first 13312B overlaid by xs
    u16   P[4 * 16 * PPAD];      // per wave unnormalized exp [n][m pad 20]
    float bias_s[16 * 16];       // adj*scale*log2e; -1e30 for m>=12; 0 for n>=12
    float bvec[4 * 128];         // bq | bk | bv | bo
    float rls[4 * 16];           // per wave: 1/rowsum for each n
};                               // 52,480 B -> 3 WG/CU (limit 54,613)

__device__ __forceinline__ u16 f2b(float f) {   // fp32 -> bf16 RNE
    unsigned u = __builtin_bit_cast(unsigned, f);
    return (u16)((u + 0x7fffu + ((u >> 16) & 1u)) >> 16);
}

__device__ __forceinline__ void st4(u16* p, float a, float b, float c, float d) {
    ushort4 v; v.x = f2b(a); v.y = f2b(b); v.z = f2b(c); v.w = f2b(d);
    *(ushort4*)p = v;   // ds_write_b64
}

__device__ __forceinline__ bf16x8 pack8(float4 a, float4 b) {
    bf16x8 r;
    r[0] = (short)f2b(a.x); r[1] = (short)f2b(a.y);
    r[2] = (short)f2b(a.z); r[3] = (short)f2b(a.w);
    r[4] = (short)f2b(b.x); r[5] = (short)f2b(b.y);
    r[6] = (short)f2b(b.z); r[7] = (short)f2b(b.w);
    return r;
}

// zero-VGPR global->LDS: lane i lands at l + i*16 bytes (wave-uniform l)
__device__ __forceinline__ void stage16(const u16* g, u16* l) {
    __builtin_amdgcn_global_load_lds(
        (const __attribute__((address_space(1))) void*)g,
        (__attribute__((address_space(3))) void*)l, 16, 0, 0);
}

// barrier with LDS-only drain: global loads/stores stay in flight
__device__ __forceinline__ void bar_lgkm() {
    asm volatile("s_waitcnt lgkmcnt(0)" ::: "memory");
    __builtin_amdgcn_sched_barrier(0);
    __builtin_amdgcn_s_barrier();
    __builtin_amdgcn_sched_barrier(0);
}

__global__ void prep_w(const float* __restrict__ Wq, const float* __restrict__ Wk,
                       const float* __restrict__ Wv, const float* __restrict__ Wo,
                       u16* __restrict__ wbf) {
    int i = blockIdx.x * 256 + threadIdx.x;     // 0..16383
    wbf[i]         = f2b(Wq[i]);
    wbf[16384 + i] = f2b(Wk[i]);
    wbf[32768 + i] = f2b(Wv[i]);
    wbf[49152 + i] = f2b(Wo[i]);
}

__global__ void prep_x(const float* __restrict__ x, u16* __restrict__ xbf) {
    size_t i = ((size_t)blockIdx.x * 256 + threadIdx.x) * 8;   // 8 elems/thread
    float4 a = *(const float4*)(x + i);
    float4 b = *(const float4*)(x + i + 4);
    *(bf16x8*)(xbf + i) = pack8(a, b);          // same RNE as in-kernel pack
}

template <bool STAGE>
__global__ __launch_bounds__(256, 3) void cja_main(
    const float* __restrict__ x, const u16* __restrict__ xbf,
    const float* __restrict__ vis,
    const float* __restrict__ bq, const float* __restrict__ bk,
    const float* __restrict__ bv, const float* __restrict__ bo,
    const float* __restrict__ bias_scale, const float* __restrict__ adj,
    const u16* __restrict__ wbf, float* __restrict__ out)
{
    extern __shared__ char smraw[];
    SMem& sm = *(SMem*)smraw;

    const int tid  = threadIdx.x;
    const int wave = tid >> 6;
    const int lane = tid & 63;
    const int lq   = lane >> 4;      // quadrant 0..3
    const int lm   = lane & 15;      // 0..15

    u16* xs = (u16*)sm.vT;           // staged-x overlay: xs[48][136] bf16

    // per-lane stage source offsets (u16 units into a group's xbf block):
    // chunk ci covers xs u16 positions [ci*512, ci*512+512); this lane's slot
    // is p = ci*512 + lane*8 -> (row, col) in the padded [48][136] layout.
    int srcoff[4];
    #pragma unroll
    for (int i = 0; i < 4; i++) {
        int ci  = wave + i * 4;
        int p   = ci * 512 + lane * 8;
        int row = p / 136; if (row > 47) row = 47;      // tail clamp (in-bounds garbage)
        int col = (p - row * 136) & 127;                // pad cols -> harmless dup
        srcoff[i] = row * 128 + col;
    }
    auto issue_stage = [&](int grp) {
        const u16* gb = xbf + (size_t)grp * (ROWS * 128);
        #pragma unroll
        for (int i = 0; i < 4; i++) {
            int ci = wave + i * 4;                      // 13 chunks over 4 waves
            if (ci < XS_CHUNKS) stage16(gb + srcoff[i], xs + ci * 512);
        }
    };

    if constexpr (STAGE) issue_stage(blockIdx.x);       // round-0 x flies over prologue

    // ---------------- One-time prologue -------------------------------------
    // zero vT pad cols ONLY beyond the staged 13312B (i*40+24 >= 13312 -> i>=333);
    // pads inside the staged region get finite bf16 x-garbage every round,
    // which PV multiplies by P=0 -> exact 0.
    for (int i = 333 + tid; i < BPW * 128; i += 256) {
        unsigned* d = (unsigned*)(sm.vT + i * VPAD + 12);
        d[0] = 0u; d[1] = 0u; d[2] = 0u; d[3] = 0u;
    }
    const float L2E = 1.4426950408889634f;
    {
        float scale = bias_scale[0] * L2E;
        int n = tid >> 4, m = tid & 15;
        float bval;
        if (m >= 12)     bval = -1e30f;                 // key-pad mask (exp2 -> 0)
        else if (n < 12) bval = adj[n * 12 + m] * scale;
        else             bval = 0.0f;                   // row pad: keep finite
        sm.bias_s[tid] = bval;
        if (tid < 128) {
            sm.bvec[tid]       = bq[tid];
            sm.bvec[128 + tid] = bk[tid];
            sm.bvec[256 + tid] = bv[tid];
            sm.bvec[384 + tid] = bo[tid];
        }
    }
    __syncthreads();   // full drain: round-0 stage complete, prologue visible

    // ---- round-invariant phase-2/3 addressing ------------------------------
    const int bl  = wave;
    const int nql = (lm < 12) ? lm : 11;                // clamp: no OOB reads
    const u16* qrowp = sm.qs + (bl * 12 + nql) * XPAD;
    const u16* krowp = sm.ks + (bl * 12 + nql) * XPAD;
    u16*   Pw  = sm.P + wave * (16 * PPAD);
    float* rlw = sm.rls + wave * 16;
    const u16* vTb = sm.vT + bl * (128 * VPAD);
    const int mrow0 = wave * 32 + lm;                   // weight row (feature)
    const int mrow1 = mrow0 + 16;
    float bias_b[4];
    #pragma unroll
    for (int rr = 0; rr < 4; rr++) bias_b[rr] = sm.bias_s[(lq * 4 + rr) * 16 + lm];

    #pragma unroll 1
    for (int grp = blockIdx.x; grp < NGRP; grp += GRID) {
        const int  b0      = grp * BPW;
        const bool hasNext = (grp + GRID) < NGRP;

        // ---- visibility for this round: per-wave register load -------------
        float vism;
        {
            int   j  = (lm < 12) ? lm : 0;
            float vr = vis[(size_t)(b0 + bl) * 12 + j];
            vism = (lm < 12) ? 10.0f * L2E * (1.0f - vr) : 0.0f;
        }

        // ---------------- Phase 1: fused Q/K/V GEMMs ------------------------
        {
            const u16* Wq_b = wbf;
            const u16* Wk_b = wbf + 16384;
            const u16* Wv_b = wbf + 32768;
            f32x4 accq[2][3], acck[2][3], accv[3][2];
            #pragma unroll
            for (int i = 0; i < 2; i++)
                #pragma unroll
                for (int j = 0; j < 3; j++) { accq[i][j] = (f32x4){0,0,0,0}; acck[i][j] = (f32x4){0,0,0,0}; }
            #pragma unroll
            for (int i = 0; i < 3; i++)
                #pragma unroll
                for (int j = 0; j < 2; j++) accv[i][j] = (f32x4){0,0,0,0};
            #pragma unroll
            for (int ks2 = 0; ks2 < 4; ks2++) {
                const int koff = ks2 * 32 + lq * 8;
                bf16x8 xt[3];
                if constexpr (STAGE) {
                    #pragma unroll
                    for (int nt = 0; nt < 3; nt++)      // ds_read_b128, 2-way banks (free)
                        xt[nt] = *(const bf16x8*)(xs + (nt * 16 + lm) * XPAD + koff);
                } else {
                    const float* xw = x + (size_t)b0 * 1536;
                    #pragma unroll
                    for (int nt = 0; nt < 3; nt++) {
                        const float* xp = xw + (nt * 16 + lm) * 128 + koff;
                        float4 u0 = *(const float4*)xp;
                        float4 u1 = *(const float4*)(xp + 4);
                        xt[nt] = pack8(u0, u1);
                    }
                }
                bf16x8 wq0 = *(const bf16x8*)(Wq_b + mrow0 * 128 + koff);
                bf16x8 wq1 = *(const bf16x8*)(Wq_b + mrow1 * 128 + koff);
                bf16x8 wk0 = *(const bf16x8*)(Wk_b + mrow0 * 128 + koff);
                bf16x8 wk1 = *(const bf16x8*)(Wk_b + mrow1 * 128 + koff);
                bf16x8 wv0 = *(const bf16x8*)(Wv_b + mrow0 * 128 + koff);
                bf16x8 wv1 = *(const bf16x8*)(Wv_b + mrow1 * 128 + koff);
                #pragma unroll
                for (int nt = 0; nt < 3; nt++) {
                    accq[0][nt] = MFMA(wq0, xt[nt], accq[0][nt]);   // C[e,n] = Wq . x^T
                    accq[1][nt] = MFMA(wq1, xt[nt], accq[1][nt]);
                    acck[0][nt] = MFMA(wk0, xt[nt], acck[0][nt]);
                    acck[1][nt] = MFMA(wk1, xt[nt], acck[1][nt]);
                    accv[nt][0] = MFMA(xt[nt], wv0, accv[nt][0]);   // C[n,e] = x . Wv^T
                    accv[nt][1] = MFMA(xt[nt], wv1, accv[nt][1]);
                }
            }
            // epilogue Q/K: transposed store -> q,k row-major [joint-row][feat]
            #pragma unroll
            for (int mi = 0; mi < 2; mi++) {
                const int e0 = (wave * 2 + mi) * 16 + lq * 4;
                float bq0 = sm.bvec[e0], bq1 = sm.bvec[e0+1], bq2 = sm.bvec[e0+2], bq3 = sm.bvec[e0+3];
                float bk0 = sm.bvec[128+e0], bk1 = sm.bvec[128+e0+1], bk2 = sm.bvec[128+e0+2], bk3 = sm.bvec[128+e0+3];
                #pragma unroll
                for (int nt = 0; nt < 3; nt++) {
                    const int n = nt * 16 + lm;                   // joint-row 0..47
                    st4(sm.qs + n * XPAD + e0, accq[mi][nt][0]+bq0, accq[mi][nt][1]+bq1,
                                               accq[mi][nt][2]+bq2, accq[mi][nt][3]+bq3);
                    st4(sm.ks + n * XPAD + e0, acck[mi][nt][0]+bk0, acck[mi][nt][1]+bk1,
                                               acck[mi][nt][2]+bk2, acck[mi][nt][3]+bk3);
                }
            }
            bar_lgkm();   // B1a: all waves' xs reads retired -> vT overlay writable
            // epilogue V: scatter -> vT[batch][feat][joint], stride 20 (conflict-free)
            #pragma unroll
            for (int nt2 = 0; nt2 < 2; nt2++) {
                const int e = (wave * 2 + nt2) * 16 + lm;         // feature column
                const float bvv = sm.bvec[256 + e];
                #pragma unroll
                for (int mt = 0; mt < 3; mt++) {
                    #pragma unroll
                    for (int r = 0; r < 4; r++) {
                        int n = mt * 16 + lq * 4 + r;             // joint-row 0..47
                        int bb = n / 12, j = n - bb * 12;
                        sm.vT[bb * (128 * VPAD) + e * VPAD + j] = f2b(accv[mt][nt2][r] + bvv);
                    }
                }
            }
        }
        bar_lgkm();   // B1: q/k/vT visible WG-wide (global ops stay in flight)

        // ---------------- Phase 2: attention (wave w owns batch w) ----------
        {
            const float SC2 = 0.2550348606381560f;        // (1/sqrt(32))*log2(e)
            const bf16x8 z8 = {0,0,0,0,0,0,0,0};
            #pragma unroll
            for (int h = 0; h < 4; h++) {
                bf16x8 qa = *(const bf16x8*)(qrowp + h * 32 + lq * 8);
                bf16x8 kb = *(const bf16x8*)(krowp + h * 32 + lq * 8);
                f32x4 sc = MFMA(qa, kb, ((f32x4){0,0,0,0}));      // scores[n,m]
                #pragma unroll
                for (int r = 0; r < 4; r++) {
                    float s2 = sc[r] * SC2 + bias_b[r] - vism;    // base-2 domain
                    float e  = __builtin_amdgcn_exp2f(s2);        // 0 exactly for pads
                    float l  = e;
                    l += __shfl_xor(l, 1, 16);
                    l += __shfl_xor(l, 2, 16);
                    l += __shfl_xor(l, 4, 16);
                    l += __shfl_xor(l, 8, 16);
                    Pw[(lq * 4 + r) * PPAD + lm] = f2b(e);        // unnormalized
                    if (lm == 0) rlw[lq * 4 + r] = __builtin_amdgcn_rcpf(l);
                }
                float rln = rlw[lm];                              // 1/l for col n=lm
                bf16x8 pb = z8;                                   // quads 2,3 = zero (K-ext 16)
                if (lq < 2) {
                    const bf16x4* pp = (const bf16x4*)(Pw + lm * PPAD + lq * 8);
                    pb = __builtin_shufflevector(pp[0], pp[1], 0, 1, 2, 3, 4, 5, 6, 7);
                }
                #pragma unroll
                for (int mt = 0; mt < 2; mt++) {
                    bf16x8 va = z8;
                    if (lq < 2) {                          // pads: P=0 kills any garbage
                        const bf16x4* vp2 = (const bf16x4*)(vTb + (h * 32 + mt * 16 + lm) * VPAD + lq * 8);
                        va = __builtin_shufflevector(vp2[0], vp2[1], 0, 1, 2, 3, 4, 5, 6, 7);
                    }
                    f32x4 c = MFMA(va, pb, ((f32x4){0,0,0,0}));   // C[e',n]
                    if (lm < 12) {                                 // ctx overlays qs
                        u16* d = sm.qs + (bl * 12 + lm) * XPAD + h * 32 + mt * 16 + lq * 4;
                        st4(d, c[0] * rln, c[1] * rln, c[2] * rln, c[3] * rln);
                    }
                }
            }
        }
        bar_lgkm();   // B2: ctx visible; vT/xs region free -> stage next round

        // ---------------- Phase 3: stage next x, Wo GEMM, store -------------
        {
            if constexpr (STAGE) { if (hasNext) issue_stage(grp + GRID); }

            const u16* Wo_b = wbf + 49152;
            f32x4 acc[2][3];
            #pragma unroll
            for (int i = 0; i < 2; i++)
                #pragma unroll
                for (int j = 0; j < 3; j++) acc[i][j] = (f32x4){0,0,0,0};
            #pragma unroll
            for (int ks2 = 0; ks2 < 4; ks2++) {
                const int koff = ks2 * 32 + lq * 8;
                bf16x8 a0 = *(const bf16x8*)(Wo_b + mrow0 * 128 + koff);
                bf16x8 a1 = *(const bf16x8*)(Wo_b + mrow1 * 128 + koff);
                #pragma unroll
                for (int nt = 0; nt < 3; nt++) {
                    bf16x8 bfr = *(const bf16x8*)(sm.qs + (nt * 16 + lm) * XPAD + koff);
                    acc[0][nt] = MFMA(a0, bfr, acc[0][nt]);
                    acc[1][nt] = MFMA(a1, bfr, acc[1][nt]);
                }
            }
            #pragma unroll
            for (int mi = 0; mi < 2; mi++) {
                const int e0 = (wave * 2 + mi) * 16 + lq * 4;
                float bo0 = sm.bvec[384+e0], bo1 = sm.bvec[384+e0+1],
                      bo2 = sm.bvec[384+e0+2], bo3 = sm.bvec[384+e0+3];
                #pragma unroll
                for (int nt = 0; nt < 3; nt++) {
                    const int n = nt * 16 + lm;                    // joint-row 0..47
                    float4 o;
                    o.x = acc[mi][nt][0] + bo0;
                    o.y = acc[mi][nt][1] + bo1;
                    o.z = acc[mi][nt][2] + bo2;
                    o.w = acc[mi][nt][3] + bo3;
                    *(float4*)(out + ((size_t)(b0 * 12 + n) << 7) + e0) = o;
                }
            }
        }
        if (hasNext) __syncthreads();   // B3 (full): stage drained, qs/ks/vT reusable
    }
}

extern "C" void kernel_launch(void* const* d_in, const int* in_sizes, int n_in,
                              void* d_out, int out_size, void* d_ws, size_t ws_size,
                              hipStream_t stream) {
    const float* x   = (const float*)d_in[0];
    const float* vis = (const float*)d_in[1];
    const float* Wq  = (const float*)d_in[2];
    const float* bq  = (const float*)d_in[3];
    const float* Wk  = (const float*)d_in[4];
    const float* bk  = (const float*)d_in[5];
    const float* Wv  = (const float*)d_in[6];
    const float* bv  = (const float*)d_in[7];
    const float* Wo  = (const float*)d_in[8];
    const float* bo  = (const float*)d_in[9];
    const float* bs  = (const float*)d_in[10];
    const float* adj = (const float*)d_in[11];
    u16* wbf = (u16*)d_ws;               // 4 x 128x128 bf16 = 128 KB
    u16* xbf = wbf + 65536;              // 16384*12*128 bf16 = 48 MB

    const size_t need = 131072 + (size_t)16384 * 12 * 128 * 2;

    prep_w<<<64, 256, 0, stream>>>(Wq, Wk, Wv, Wo, wbf);
    if (ws_size >= need) {
        prep_x<<<12288, 256, 0, stream>>>(x, xbf);
        cja_main<true><<<GRID, 256, sizeof(SMem), stream>>>(
            x, xbf, vis, bq, bk, bv, bo, bs, adj, wbf, (float*)d_out);
    } else {
        cja_main<false><<<GRID, 256, sizeof(SMem), stream>>>(
            x, xbf, vis, bq, bk, bv, bo, bs, adj, wbf, (float*)d_out);
    }
}